// Round 1
// 198.118 us; speedup vs baseline: 1.0281x; 1.0281x over previous
//
#include <hip/hip_runtime.h>
#include <math.h>

#define EMB 256
#define NS 256
#define BATCH_SZ 16384
#define ROWS 16            // batch rows per block
#define LDA 264            // padded LDS row stride (bf16 elems)
#define NBLK (BATCH_SZ / ROWS)   // 1024 main blocks

typedef __attribute__((ext_vector_type(8))) __bf16 bf16x8;
typedef __attribute__((ext_vector_type(4))) float  f32x4;

// log(NS * logUniformProb(id))
__device__ __forceinline__ float log_corr(int id) {
    const float INV_LOG_RANGE = 1.0f / 11.5129354649f;  // 1/ln(100001)
    float p = log1pf(1.0f / ((float)id + 1.0f)) * INV_LOG_RANGE;
    return logf((float)NS * p);
}
__device__ __forceinline__ unsigned short f2bf(float x) {
    unsigned int u = __float_as_uint(x);
    u += 0x7FFFu + ((u >> 16) & 1u);
    return (unsigned short)(u >> 16);
}
__device__ __forceinline__ float bf2f(unsigned short b) {
    return __uint_as_float(((unsigned int)b) << 16);
}
// fast softplus(-|x|): log1p(exp(-a)), a>=0. HW exp/log; err < 1e-7 absolute.
__device__ __forceinline__ float softplus_neg(float a) {
    return __logf(1.0f + __expf(-a));
}

// ---- prep: gather sampled weight rows into MFMA-fragment-swizzled bf16 B ----
// Bsw element (T, kb, lane, j) = W[s = T*16 + (lane&15)][k = kb*32 + (lane>>4)*8 + j]
extern "C" __global__ void __launch_bounds__(64)
nce_prep(const float* __restrict__ nce_weights,
         const float* __restrict__ nce_biases,
         const int*   __restrict__ sampled_ids,
         unsigned short* __restrict__ Bsw,
         float* __restrict__ scws)
{
    const int tid = blockIdx.x * 64 + threadIdx.x;   // 0..8191
    const int s   = tid >> 5;                        // sample 0..255
    const int u   = tid & 31;                        // 8-elem k-chunk 0..31
    const int sid = sampled_ids[s];
    const float4* wr = (const float4*)(nce_weights + (size_t)sid * EMB + u * 8);
    float4 a = wr[0], b = wr[1];
    unsigned short o[8] = { f2bf(a.x), f2bf(a.y), f2bf(a.z), f2bf(a.w),
                            f2bf(b.x), f2bf(b.y), f2bf(b.z), f2bf(b.w) };
    const int T = s >> 4, kb = u >> 2;
    const int lane = ((u & 3) << 4) | (s & 15);
    unsigned short* dst = Bsw + ((size_t)((T * 8 + kb) * 64 + lane)) * 8;
    *(ushort4*)(dst)     = *(ushort4*)&o[0];
    *(ushort4*)(dst + 4) = *(ushort4*)&o[4];
    if (u == 0) scws[s] = nce_biases[sid] - log_corr(sid);
}

// ---- main: 1024 blocks x 256 thr; block = 16 batch rows x all 256 samples ----
extern "C" __global__ void __launch_bounds__(256, 4)
nce_main(const float* __restrict__ embeddings,
         const float* __restrict__ nce_weights,
         const float* __restrict__ nce_biases,
         const int*   __restrict__ inputs,
         const int*   __restrict__ labels,
         const unsigned short* __restrict__ Bsw,
         const float* __restrict__ scws,
         float* __restrict__ out_embed,
         float* __restrict__ partials)
{
    __shared__ unsigned short A[ROWS * LDA];   // 8.25 KB bf16 embed tile
    __shared__ float sc_l[NS];
    __shared__ float wpart[4];

    const int t    = threadIdx.x;
    const int lane = t & 63;
    const int wv   = t >> 6;
    const int b0   = blockIdx.x * ROWS;
    const int l15  = lane & 15;
    const int lq   = lane >> 4;

    sc_l[t] = scws[t];

    // One coalesced 64B index/label load per wave; lane r holds row b0+r's value.
    const int idxv = inputs[b0 + l15];
    const int labv = labels[b0 + l15];

    // Phase A+B fused: wave wv owns rows {i*4+wv}. Issue ALL gather streams
    // (embed row, label-weight row, bias word) up-front for max MLP; true-logit
    // dot uses the register copy of the embed row — no LDS round-trip, no
    // barrier between A and B.
    f32x4 v[4], w[4];
    float bias[4], corr[4];
    #pragma unroll
    for (int i = 0; i < 4; ++i) {
        int r   = i * 4 + wv;
        int idx = __shfl(idxv, r, 64);
        int lab = __shfl(labv, r, 64);
        v[i] = __builtin_nontemporal_load(
                   (const f32x4*)(embeddings + (size_t)idx * EMB) + lane);
        w[i] = __builtin_nontemporal_load(
                   (const f32x4*)(nce_weights + (size_t)lab * EMB) + lane);
        bias[i] = nce_biases[lab];          // uniform addr -> one line, L2-hot
        corr[i] = log_corr(lab);            // VALU, wave-redundant (free)
    }

    float myloss = 0.0f;

    #pragma unroll
    for (int i = 0; i < 4; ++i) {
        int r = i * 4 + wv;
        // streaming copy-out (nontemporal: don't evict Bsw/scws from L2)
        __builtin_nontemporal_store(v[i],
            (f32x4*)(out_embed + (size_t)(b0 + r) * EMB) + lane);
        // bf16 pack into the MFMA A-tile
        ushort4 o;
        o.x = f2bf(v[i].x); o.y = f2bf(v[i].y);
        o.z = f2bf(v[i].z); o.w = f2bf(v[i].w);
        *(ushort4*)(A + r * LDA + lane * 4) = o;
        // true logit: dot over 256 elems (register embed row x gathered w row)
        float p = v[i].x * w[i].x + v[i].y * w[i].y +
                  v[i].z * w[i].z + v[i].w * w[i].w;
        #pragma unroll
        for (int o2 = 32; o2 > 0; o2 >>= 1) p += __shfl_down(p, o2, 64);
        if (lane == 0) {
            float tl = p + bias[i] - corr[i];
            myloss += fmaxf(tl, 0.0f) - tl + softplus_neg(fabsf(tl));
        }
    }
    __syncthreads();

    // Phase C: MFMA; wave wv owns all 16 rows x samples wv*64..wv*64+63.
    const unsigned short* Arow = A + l15 * LDA + lq * 8;
    const bf16x8* Bv = (const bf16x8*)Bsw;

    f32x4 acc[4];
    #pragma unroll
    for (int tt = 0; tt < 4; ++tt) acc[tt] = (f32x4){0.f, 0.f, 0.f, 0.f};

    #pragma unroll
    for (int kb = 0; kb < 8; ++kb) {
        bf16x8 af = *(const bf16x8*)(Arow + kb * 32);       // ds_read_b128
        #pragma unroll
        for (int tt = 0; tt < 4; ++tt) {
            int T = wv * 4 + tt;
            bf16x8 bfm = Bv[(T * 8 + kb) * 64 + lane];      // 1KB/wave, L2-hit
            acc[tt] = __builtin_amdgcn_mfma_f32_16x16x32_bf16(af, bfm, acc[tt], 0, 0, 0);
        }
    }

    // Epilogue: x = acc + sc[n]; xent label=0
    #pragma unroll
    for (int tt = 0; tt < 4; ++tt) {
        float scv = sc_l[wv * 64 + tt * 16 + l15];
        #pragma unroll
        for (int i = 0; i < 4; ++i) {
            float x = acc[tt][i] + scv;
            myloss += fmaxf(x, 0.0f) + softplus_neg(fabsf(x));
        }
    }

    // block reduce + ONE plain store per block
    #pragma unroll
    for (int o = 32; o > 0; o >>= 1) myloss += __shfl_down(myloss, o, 64);
    if (lane == 0) wpart[wv] = myloss;
    __syncthreads();
    if (t == 0)
        partials[blockIdx.x] = wpart[0] + wpart[1] + wpart[2] + wpart[3];
}

// ---- final: reduce 1024 partials -> out_cost ----
extern "C" __global__ void __launch_bounds__(256)
nce_final(const float* __restrict__ partials, float* __restrict__ out_cost)
{
    __shared__ float wpart[4];
    const int t    = threadIdx.x;
    const int lane = t & 63;
    const int wv   = t >> 6;
    float s = 0.0f;
    #pragma unroll
    for (int i = 0; i < NBLK / 256; ++i) s += partials[i * 256 + t];
    #pragma unroll
    for (int o = 32; o > 0; o >>= 1) s += __shfl_down(s, o, 64);
    if (lane == 0) wpart[wv] = s;
    __syncthreads();
    if (t == 0)
        *out_cost = (wpart[0] + wpart[1] + wpart[2] + wpart[3]) * (1.0f / (float)BATCH_SZ);
}

extern "C" void kernel_launch(void* const* d_in, const int* in_sizes, int n_in,
                              void* d_out, int out_size, void* d_ws, size_t ws_size,
                              hipStream_t stream) {
    const float* embeddings  = (const float*)d_in[0];
    const float* nce_weights = (const float*)d_in[1];
    const float* nce_biases  = (const float*)d_in[2];
    const int*   inputs      = (const int*)d_in[3];
    const int*   labels      = (const int*)d_in[4];
    const int*   sampled_ids = (const int*)d_in[5];

    float* out      = (float*)d_out;
    float* out_cost = out + (size_t)BATCH_SZ * EMB;

    unsigned short* Bsw      = (unsigned short*)d_ws;                  // 128 KB
    float*          scws     = (float*)((char*)d_ws + NS * EMB * sizeof(unsigned short));
    float*          partials = scws + NS;                              // 4 KB

    nce_prep<<<NS * 32 / 64, 64, 0, stream>>>(
        nce_weights, nce_biases, sampled_ids, Bsw, scws);

    nce_main<<<NBLK, 256, 0, stream>>>(
        embeddings, nce_weights, nce_biases, inputs, labels,
        Bsw, scws, out, partials);

    nce_final<<<1, 256, 0, stream>>>(partials, out_cost);
}